// Round 13
// baseline (70.542 us; speedup 1.0000x reference)
//
#include <hip/hip_runtime.h>
#include <hip/hip_bf16.h>

typedef __bf16 bf16x8 __attribute__((ext_vector_type(8)));
typedef float  f32x4  __attribute__((ext_vector_type(4)));

#define HW       3136
#define IMG_W    56
#define IMG_H    56
#define XT_ROW_B 16384                     // 64 cols * 128ch * 2B
#define XT_IMG_B (58*XT_ROW_B)             // 950272
#define XT_BYTES ((size_t)32*XT_IMG_B)     // ~30.4 MB
#define WGRAN    (9*128*16)                // 16B granules in W (18432)
#define WB_BYTES ((size_t)WGRAN*16)        // 294912
#define PBLK     (32*58)                   // xprep blocks (1856)
#define WBLK     (WGRAN/256)               // wcvt blocks (72)
#define CBLK     224                       // conv blocks: 7/img, 8 out-rows each

#define AS1 __attribute__((address_space(1)))
#define AS3 __attribute__((address_space(3)))

// ---- fused prep: blocks [0,PBLK) convert x -> xt; blocks [PBLK,..) convert W ----
// xt: [n][58 rows][64 cols][128 ch] bf16, zero borders, ((col&7) XOR) swizzle baked in.
// wb: fragment-major [tap][q32][c][f][lq][l15] 16B granules.
__global__ __launch_bounds__(256) void prep_kernel(const float* __restrict__ x,
                                                   unsigned char* __restrict__ xt,
                                                   const float* __restrict__ w,
                                                   unsigned char* __restrict__ wb) {
    const int bid = blockIdx.x;
    const int t = threadIdx.x;

    if (bid >= PBLK) {                    // ---- weight convert part ----
        int i = (bid - PBLK) * 256 + t;   // one 16B granule each
        if (i >= WGRAN) return;
        const int l15 = i & 15, lq = (i >> 4) & 3, f = (i >> 6) & 1;
        const int c   = (i >> 7) & 3, q32 = (i >> 9) & 3, tap = i >> 11;
        const int oc = q32 * 32 + f * 16 + l15;
        const int ch = c * 32 + lq * 8;
        const float* src = w + (size_t)(tap * 128 + oc) * 128 + ch;
        bf16x8 v;
        #pragma unroll
        for (int j = 0; j < 8; ++j) v[j] = (__bf16)src[j];
        *(bf16x8*)(wb + (size_t)i * 16) = v;
        return;
    }

    // ---- x prep part ----
    __shared__ float ldsF[128 * 65];
    const int swz = (bid & 7) * (PBLK / 8) + (bid >> 3);
    const int n = swz / 58, rt = swz - n * 58;
    unsigned char* row = xt + (size_t)n * XT_IMG_B + (size_t)rt * XT_ROW_B;

    if (rt == 0 || rt == 57) {            // zero border rows
        f32x4 z = {0.f, 0.f, 0.f, 0.f};
        #pragma unroll
        for (int i = 0; i < 4; ++i) *(f32x4*)(row + t * 64 + i * 16) = z;
        return;
    }
    const int r = rt - 1;
    const float* xr = x + (size_t)n * 128 * HW + (size_t)r * IMG_W;
    const int wv = t >> 6, lane = t & 63;
    const int wi = min(lane, IMG_W - 1);
    #pragma unroll
    for (int cc = 0; cc < 32; ++cc) {
        int c = cc * 4 + wv;
        float v = xr[(size_t)c * HW + wi];
        ldsF[c * 65 + lane] = (lane < IMG_W) ? v : 0.f;
    }
    __syncthreads();

    const int cl = t >> 2, q = t & 3;     // col 0..63, channel quarter
    const bool inb = (cl >= 1) && (cl <= 56);
    #pragma unroll
    for (int g4 = 0; g4 < 4; ++g4) {
        int gi = q * 4 + g4;              // granule = channels gi*8..gi*8+7
        bf16x8 pk;
        #pragma unroll
        for (int j = 0; j < 8; ++j)
            pk[j] = inb ? (__bf16)ldsF[(gi * 8 + j) * 65 + (cl - 1)] : (__bf16)0.0f;
        *(bf16x8*)(row + cl * 256 + ((gi ^ (cl & 7)) * 16)) = pk;
    }
}

// ---- conv: 224 blocks, ONE 8-row tile (448 pos = 28 frags);
//      896 threads = 14 waves = 2 oc-halves (64 oc, f=4) x 7 pos-groups (K=4);
//      full 10-row window staged once (160KB LDS); A ring-dbuf over 36 steps ----
__global__ __launch_bounds__(896, 1) void conv_kernel(const unsigned char* __restrict__ xt,
                                                      const unsigned char* __restrict__ wb,
                                                      float* __restrict__ out) {
    __shared__ __align__(16) unsigned char xs[163840];      // 10 row-slots x 16KB
    const int t = threadIdx.x, lane = t & 63, wv = t >> 6;  // 14 waves
    const int l15 = lane & 15, lq = lane >> 4;
    const int b = blockIdx.x;
    const int swz = (b & 7) * 28 + (b >> 3);                // XCD-contiguous: 4 img/XCD
    const int img = swz / 7, loc = swz - img * 7;
    const int obase = loc * 8;                              // out rows obase..obase+7

    // prologue: stage all 10 slots (10240 x 16B granules) linearly; drain; barrier
    const unsigned char* src = xt + (size_t)img * XT_IMG_B + (size_t)obase * XT_ROW_B;
    #pragma unroll
    for (int it = 0; it < 11; ++it) {                       // 11*896 = 9856 granules
        const int gx = it * 896 + t;
        __builtin_amdgcn_global_load_lds(
            (const AS1 unsigned int*)(src + (size_t)gx * 16),
            (AS3 unsigned int*)(xs + (size_t)gx * 16), 16, 0, 0);
    }
    if (wv < 6) {                                           // tail 384 granules, full waves
        const int gx = 9856 + t;
        __builtin_amdgcn_global_load_lds(
            (const AS1 unsigned int*)(src + (size_t)gx * 16),
            (AS3 unsigned int*)(xs + (size_t)gx * 16), 16, 0, 0);
    }
    asm volatile("s_waitcnt vmcnt(0)" ::: "memory");
    __builtin_amdgcn_sched_barrier(0);
    __builtin_amdgcn_s_barrier();
    __builtin_amdgcn_sched_barrier(0);

    const int och = wv & 1;                                 // 64-oc half
    const int g   = wv >> 1;                                // pos-group 0..6
    const unsigned char* wt = wb + (size_t)och * 16384 + lane * 16;

    int base_[4], pr_[4], pc_[4];
    #pragma unroll
    for (int k = 0; k < 4; ++k) {
        int p = (g * 4 + k) * 16 + l15;                     // 0..447 tile-local pos
        int pr = p / 56, pc = p - pr * 56;
        pr_[k] = pr; pc_[k] = pc;
        base_[k] = (pr + 1) * 16384 + (pc + 1) * 256;
    }

    f32x4 acc[4][4];
    #pragma unroll
    for (int f = 0; f < 4; ++f)
        #pragma unroll
        for (int k = 0; k < 4; ++k) acc[f][k] = (f32x4){0.f, 0.f, 0.f, 0.f};

    // A ring double-buffer over 36 (tap,c) steps; 4 frags (64 oc) per step.
    // frag(f) byte addr = wt + tap*32768 + (f>>1)*8192 + (c*2+(f&1))*1024
    bf16x8 aB[2][4];
    #pragma unroll
    for (int f = 0; f < 4; ++f)
        aB[0][f] = *(const bf16x8*)(wt + (f >> 1) * 8192 + (f & 1) * 1024);

    #pragma unroll
    for (int tc = 0; tc < 36; ++tc) {
        const int tap = tc >> 2, c = tc & 3;
        if (tc < 35) {                    // prefetch next step's 4 A-frags
            const int t2 = (tc + 1) >> 2, c2 = (tc + 1) & 3;
            #pragma unroll
            for (int f = 0; f < 4; ++f)
                aB[(tc + 1) & 1][f] = *(const bf16x8*)(wt + t2 * 32768 + (f >> 1) * 8192
                                                       + (c2 * 2 + (f & 1)) * 1024);
        }
        __builtin_amdgcn_sched_barrier(0);   // pin load-issue before the MFMA cluster

        const int dh = tap / 3 - 1, dw = tap - (tap / 3) * 3 - 1;
        const int offb = dh * 16384 + dw * 256;
        __builtin_amdgcn_s_setprio(1);
        #pragma unroll
        for (int k = 0; k < 4; ++k) {
            int sw = (pc_[k] + 1 + dw) & 7;
            int gi = ((c * 4 + lq) ^ sw) * 16;
            bf16x8 bf = *(const bf16x8*)(xs + base_[k] + offb + gi);
            acc[0][k] = __builtin_amdgcn_mfma_f32_16x16x32_bf16(aB[tc & 1][0], bf, acc[0][k], 0, 0, 0);
            acc[1][k] = __builtin_amdgcn_mfma_f32_16x16x32_bf16(aB[tc & 1][1], bf, acc[1][k], 0, 0, 0);
            acc[2][k] = __builtin_amdgcn_mfma_f32_16x16x32_bf16(aB[tc & 1][2], bf, acc[2][k], 0, 0, 0);
            acc[3][k] = __builtin_amdgcn_mfma_f32_16x16x32_bf16(aB[tc & 1][3], bf, acc[3][k], 0, 0, 0);
        }
        __builtin_amdgcn_s_setprio(0);
        __builtin_amdgcn_sched_barrier(0);
    }

    float* on = out + (size_t)img * 128 * HW;
    #pragma unroll
    for (int f = 0; f < 4; ++f)
        #pragma unroll
        for (int k = 0; k < 4; ++k) {
            int pos = (obase + pr_[k]) * 56 + pc_[k];
            int oc  = och * 64 + f * 16 + lq * 4;
            #pragma unroll
            for (int rr = 0; rr < 4; ++rr)
                on[(size_t)(oc + rr) * HW + pos] = acc[f][k][rr];
        }
}

// ================= fallback (ws too small): self-contained, fp32 weights =================
#define PITCH  272
#define LDSB   (4*64*PITCH)
#define NBLK   896

template<int NPF>
__device__ __forceinline__ void fb_compute(const unsigned char* xs, const float* wf,
                                           float* on, int oc0, int pf0, int r0, int lane) {
    const int l15 = lane & 15, lq = lane >> 4;
    int spb[NPF];
    #pragma unroll
    for (int k = 0; k < NPF; ++k) {
        int p = (pf0 + k) * 16 + l15;
        int r = p / 56, w = p - r * 56;
        spb[k] = ((r + 1) * 64 + (w + 1)) * PITCH + lq * 16;
    }
    f32x4 acc[2][NPF];
    #pragma unroll
    for (int f = 0; f < 2; ++f)
        #pragma unroll
        for (int k = 0; k < NPF; ++k) acc[f][k] = (f32x4){0.f, 0.f, 0.f, 0.f};
    #pragma unroll 3
    for (int tap = 0; tap < 9; ++tap) {
        const int offb  = ((tap / 3) * 64 + (tap % 3) - 65) * PITCH;
        const int wbase = tap * 16384 + oc0 * 128 + l15 * 128 + lq * 8;
        #pragma unroll
        for (int c = 0; c < 4; ++c) {
            bf16x8 a[2];
            #pragma unroll
            for (int f = 0; f < 2; ++f) {
                const float* p = wf + wbase + f * 2048 + c * 32;
                #pragma unroll
                for (int j = 0; j < 8; ++j) a[f][j] = (__bf16)p[j];
            }
            #pragma unroll
            for (int k = 0; k < NPF; ++k) {
                bf16x8 b = *(const bf16x8*)(xs + spb[k] + offb + c * 64);
                #pragma unroll
                for (int f = 0; f < 2; ++f)
                    acc[f][k] = __builtin_amdgcn_mfma_f32_16x16x32_bf16(a[f], b, acc[f][k], 0, 0, 0);
            }
        }
    }
    #pragma unroll
    for (int f = 0; f < 2; ++f)
        #pragma unroll
        for (int k = 0; k < NPF; ++k) {
            int pos = r0 * 56 + (pf0 + k) * 16 + l15;
            int oc  = oc0 + f * 16 + lq * 4;
            #pragma unroll
            for (int rr = 0; rr < 4; ++rr)
                on[(size_t)(oc + rr) * HW + pos] = acc[f][k][rr];
        }
}

__global__ __launch_bounds__(512, 4) void fb_conv_kernel(const float* __restrict__ x,
                                                         const float* __restrict__ wf,
                                                         float* __restrict__ out) {
    __shared__ __align__(16) unsigned char xs[LDSB];
    const int tid = threadIdx.x, lane = tid & 63, wv = tid >> 6;
    const int bid = blockIdx.x;
    const int swz = (bid & 7) * (NBLK / 8) + (bid >> 3);
    const int n = swz / 28, rp = swz - n * 28, r0 = rp * 2;
    if (wv < 4) {
        const float* xn = x + (size_t)n * 128 * HW;
        const int ar = r0 - 1 + wv, wi = lane - 1;
        const bool v = (ar >= 0) & (ar < IMG_H) & (wi >= 0) & (wi < IMG_W);
        const int gc = min(max(ar, 0), IMG_H - 1) * IMG_W + min(max(wi, 0), IMG_W - 1);
        unsigned char* dst = xs + (wv * 64 + lane) * PITCH;
        #pragma unroll
        for (int cg = 0; cg < 16; ++cg) {
            bf16x8 pk;
            #pragma unroll
            for (int j = 0; j < 8; ++j) {
                float f = xn[(size_t)(cg * 8 + j) * HW + gc];
                pk[j] = (__bf16)(v ? f : 0.f);
            }
            *(bf16x8*)(dst + cg * 16) = pk;
        }
    }
    __syncthreads();
    const int oc0 = (wv & 3) * 32;
    float* on = out + (size_t)n * 128 * HW;
    if (wv < 4) fb_compute<4>(xs, wf, on, oc0, 0, r0, lane);
    else        fb_compute<3>(xs, wf, on, oc0, 4, r0, lane);
}

extern "C" void kernel_launch(void* const* d_in, const int* in_sizes, int n_in,
                              void* d_out, int out_size, void* d_ws, size_t ws_size,
                              hipStream_t stream) {
    const float* x = (const float*)d_in[0];
    const float* w = (const float*)d_in[1];
    float* out = (float*)d_out;

    if (ws_size >= XT_BYTES + WB_BYTES) {
        unsigned char* xt = (unsigned char*)d_ws;
        unsigned char* wb = xt + XT_BYTES;
        prep_kernel<<<PBLK + WBLK, 256, 0, stream>>>(x, xt, w, wb);
        conv_kernel<<<CBLK, 896, 0, stream>>>(xt, wb, out);
    } else {
        fb_conv_kernel<<<NBLK, 512, 0, stream>>>(x, w, out);
    }
}

// Round 14
// 50.331 us; speedup vs baseline: 1.4016x; 1.4016x over previous
//
#include <hip/hip_runtime.h>
#include <hip/hip_bf16.h>

typedef __bf16 bf16x8 __attribute__((ext_vector_type(8)));
typedef float  f32x4  __attribute__((ext_vector_type(4)));

#define HW       3136
#define IMG_W    56
#define IMG_H    56
#define WGRAN    (9*128*16)                // 16B granules in W (18432)
#define WB_BYTES ((size_t)WGRAN*16)        // 294912
#define CBLK     224                       // conv blocks: 7/img, 8 out-rows each

#define AS1 __attribute__((address_space(1)))
#define AS3 __attribute__((address_space(3)))

// ---- weight fp32 -> bf16, fragment-major [tap][q32][c][f][lq][l15] 16B granules ----
__global__ __launch_bounds__(256) void wcvt_kernel(const float* __restrict__ w,
                                                   unsigned char* __restrict__ wb) {
    int i = blockIdx.x * 256 + threadIdx.x;          // one 16B granule each
    if (i >= WGRAN) return;
    const int l15 = i & 15, lq = (i >> 4) & 3, f = (i >> 6) & 1;
    const int c   = (i >> 7) & 3, q32 = (i >> 9) & 3, tap = i >> 11;
    const int oc = q32 * 32 + f * 16 + l15;
    const int ch = c * 32 + lq * 8;
    const float* src = w + (size_t)(tap * 128 + oc) * 128 + ch;
    bf16x8 v;
    #pragma unroll
    for (int j = 0; j < 8; ++j) v[j] = (__bf16)src[j];
    *(bf16x8*)(wb + (size_t)i * 16) = v;
}

// ---- in-kernel x staging: one (slot,cg) task = 8 coalesced 224B fp32 loads ->
//      cvt -> one swizzled ds_write_b128. Zero borders via mask. ----
__device__ __forceinline__ void stage_task(unsigned char* xs, const float* __restrict__ xn,
                                           int obase, int s, int cg, int lane) {
    const int ar  = obase - 1 + s;                       // absolute image row
    const int arc = min(max(ar, 0), IMG_H - 1);
    const int wcc = min(max(lane - 1, 0), IMG_W - 1);
    const bool v  = (ar >= 0) & (ar < IMG_H) & (lane >= 1) & (lane <= IMG_W);
    const float* bp = xn + (size_t)(cg * 8) * HW + arc * IMG_W + wcc;
    bf16x8 pk;
    #pragma unroll
    for (int j = 0; j < 8; ++j) {
        float f = bp[(size_t)j * HW];
        pk[j] = (__bf16)(v ? f : 0.f);
    }
    *(bf16x8*)(xs + s * 16384 + lane * 256 + ((cg ^ (lane & 7)) * 16)) = pk;
}

// ---- compute one 4-row tile (224 pos; wave = 32 oc (f=2) x 7 frags) — r11 body.
//      STG: at taps 2 and 4, run 4 stage-tasks each for slots 6..9 (T1's tail). ----
template<bool STG>
__device__ __forceinline__ void compute_tile(unsigned char* xs, const __bf16* wt,
                                             float* on, int oc0, int g7, int tloc,
                                             int obase, int lane,
                                             const float* __restrict__ xn, int wv) {
    const int l15 = lane & 15, lq = lane >> 4;
    int vb[7], pr_[7], pc_[7];
    #pragma unroll
    for (int k = 0; k < 7; ++k) {
        int p = (g7 * 7 + k) * 16 + l15;          // 0..223 tile-local pos
        int pr = p / 56, pc = p - pr * 56;
        pr_[k] = pr; pc_[k] = pc;
        vb[k] = (4 * tloc + pr + 1) * 16384 + (pc + 1) * 256;
    }
    f32x4 acc[2][7];
    #pragma unroll
    for (int f = 0; f < 2; ++f)
        #pragma unroll
        for (int k = 0; k < 7; ++k) acc[f][k] = (f32x4){0.f, 0.f, 0.f, 0.f};

    #pragma unroll
    for (int tap = 0; tap < 9; ++tap) {
        // this tap's 8 A-frags (1KB coalesced wave-loads each)
        bf16x8 a[8];
        const __bf16* wn = wt + tap * 16384;
        #pragma unroll
        for (int i = 0; i < 8; ++i)
            a[i] = *(const bf16x8*)(wn + ((i & 3) * 2 + (i >> 2)) * 512);
        if (STG && tap == 2) {
            #pragma unroll
            for (int i = 0; i < 4; ++i) {
                int tid = 96 + wv + 8 * i;        // tasks 96..127
                stage_task(xs, xn, obase, 6 + ((tid - 96) >> 4), (tid - 96) & 15, lane);
            }
        }
        if (STG && tap == 4) {
            #pragma unroll
            for (int i = 4; i < 8; ++i) {
                int tid = 96 + wv + 8 * i;        // tasks 128..159
                stage_task(xs, xn, obase, 6 + ((tid - 96) >> 4), (tid - 96) & 15, lane);
            }
        }
        __builtin_amdgcn_sched_barrier(0);        // pin loads before MFMA cluster

        const int dh = tap / 3 - 1, dw = tap - (tap / 3) * 3 - 1;
        const int offb = dh * 16384 + dw * 256;
        int sw[7];
        #pragma unroll
        for (int k = 0; k < 7; ++k) sw[k] = (pc_[k] + 1 + dw) & 7;

        __builtin_amdgcn_s_setprio(1);
        #pragma unroll
        for (int c = 0; c < 4; ++c) {
            #pragma unroll
            for (int k = 0; k < 7; ++k) {
                int gi = ((c * 4 + lq) ^ sw[k]) * 16;
                bf16x8 b = *(const bf16x8*)(xs + vb[k] + offb + gi);
                acc[0][k] = __builtin_amdgcn_mfma_f32_16x16x32_bf16(a[c],     b, acc[0][k], 0, 0, 0);
                acc[1][k] = __builtin_amdgcn_mfma_f32_16x16x32_bf16(a[4 + c], b, acc[1][k], 0, 0, 0);
            }
        }
        __builtin_amdgcn_s_setprio(0);
        __builtin_amdgcn_sched_barrier(0);
    }

    #pragma unroll
    for (int f = 0; f < 2; ++f)
        #pragma unroll
        for (int k = 0; k < 7; ++k) {
            int pos = (obase + 4 * tloc + pr_[k]) * 56 + pc_[k];
            int oc  = oc0 + f * 16 + lq * 4;
            #pragma unroll
            for (int rr = 0; rr < 4; ++rr)
                on[(size_t)(oc + rr) * HW + pos] = acc[f][k][rr];
        }
}

// ---- conv: 224 blocks x (2 x 4-row tiles); reads x DIRECTLY (no xt prepass).
//      10 row-slots x 16KB = 160KB LDS; slots 0..5 staged in prologue,
//      slots 6..9 staged inside T0 (taps 2,4); one mid-block barrier. ----
__global__ __launch_bounds__(512, 2) void conv_kernel(const float* __restrict__ x,
                                                      const unsigned char* __restrict__ wb,
                                                      float* __restrict__ out) {
    __shared__ __align__(16) unsigned char xs[163840];      // 10 row-slots x 16KB
    const int t = threadIdx.x, lane = t & 63, wv = t >> 6;  // 8 waves
    const int b = blockIdx.x;
    const int swz = (b & 7) * 28 + (b >> 3);                // XCD-contiguous: 4 img/XCD
    const int img = swz / 7, loc = swz - img * 7;
    const int obase = loc * 8;                              // out rows obase..obase+7

    const float* xn = x + (size_t)img * 128 * HW;

    // prologue: stage slots 0..5 (96 tasks, 12 per wave), then full barrier
    #pragma unroll 3
    for (int i = 0; i < 12; ++i) {
        int tid = wv + 8 * i;                               // 0..95
        stage_task(xs, xn, obase, tid >> 4, tid & 15, lane);
    }
    __syncthreads();

    const int oc0 = (wv & 3) * 32;
    const int g7  = wv >> 2;                                // pos-half: frags 0-6 / 7-13
    const __bf16* wt = (const __bf16*)(wb + (size_t)(wv & 3) * 8192 + lane * 16);
    float* on = out + (size_t)img * 128 * HW;

    // T0 (rows obase..obase+3, slots 0..5); stages slots 6..9 at taps 2,4
    compute_tile<true>(xs, wt, on, oc0, g7, 0, obase, lane, xn, wv);

    __syncthreads();                                        // slots 6..9 ds_writes done

    // T1 (rows obase+4..obase+7, slots 4..9)
    compute_tile<false>(xs, wt, on, oc0, g7, 1, obase, lane, xn, wv);
}

// ================= fallback (ws too small): self-contained, fp32 weights =================
#define PITCH  272
#define LDSB   (4*64*PITCH)
#define NBLK   896

template<int NPF>
__device__ __forceinline__ void fb_compute(const unsigned char* xs, const float* wf,
                                           float* on, int oc0, int pf0, int r0, int lane) {
    const int l15 = lane & 15, lq = lane >> 4;
    int spb[NPF];
    #pragma unroll
    for (int k = 0; k < NPF; ++k) {
        int p = (pf0 + k) * 16 + l15;
        int r = p / 56, w = p - r * 56;
        spb[k] = ((r + 1) * 64 + (w + 1)) * PITCH + lq * 16;
    }
    f32x4 acc[2][NPF];
    #pragma unroll
    for (int f = 0; f < 2; ++f)
        #pragma unroll
        for (int k = 0; k < NPF; ++k) acc[f][k] = (f32x4){0.f, 0.f, 0.f, 0.f};
    #pragma unroll 3
    for (int tap = 0; tap < 9; ++tap) {
        const int offb  = ((tap / 3) * 64 + (tap % 3) - 65) * PITCH;
        const int wbase = tap * 16384 + oc0 * 128 + l15 * 128 + lq * 8;
        #pragma unroll
        for (int c = 0; c < 4; ++c) {
            bf16x8 a[2];
            #pragma unroll
            for (int f = 0; f < 2; ++f) {
                const float* p = wf + wbase + f * 2048 + c * 32;
                #pragma unroll
                for (int j = 0; j < 8; ++j) a[f][j] = (__bf16)p[j];
            }
            #pragma unroll
            for (int k = 0; k < NPF; ++k) {
                bf16x8 b = *(const bf16x8*)(xs + spb[k] + offb + c * 64);
                #pragma unroll
                for (int f = 0; f < 2; ++f)
                    acc[f][k] = __builtin_amdgcn_mfma_f32_16x16x32_bf16(a[f], b, acc[f][k], 0, 0, 0);
            }
        }
    }
    #pragma unroll
    for (int f = 0; f < 2; ++f)
        #pragma unroll
        for (int k = 0; k < NPF; ++k) {
            int pos = r0 * 56 + (pf0 + k) * 16 + l15;
            int oc  = oc0 + f * 16 + lq * 4;
            #pragma unroll
            for (int rr = 0; rr < 4; ++rr)
                on[(size_t)(oc + rr) * HW + pos] = acc[f][k][rr];
        }
}

__global__ __launch_bounds__(512, 4) void fb_conv_kernel(const float* __restrict__ x,
                                                         const float* __restrict__ wf,
                                                         float* __restrict__ out) {
    __shared__ __align__(16) unsigned char xs[LDSB];
    const int tid = threadIdx.x, lane = tid & 63, wv = tid >> 6;
    const int bid = blockIdx.x;
    const int swz = (bid & 7) * (NBLK / 8) + (bid >> 3);
    const int n = swz / 28, rp = swz - n * 28, r0 = rp * 2;
    if (wv < 4) {
        const float* xn = x + (size_t)n * 128 * HW;
        const int ar = r0 - 1 + wv, wi = lane - 1;
        const bool v = (ar >= 0) & (ar < IMG_H) & (wi >= 0) & (wi < IMG_W);
        const int gc = min(max(ar, 0), IMG_H - 1) * IMG_W + min(max(wi, 0), IMG_W - 1);
        unsigned char* dst = xs + (wv * 64 + lane) * PITCH;
        #pragma unroll
        for (int cg = 0; cg < 16; ++cg) {
            bf16x8 pk;
            #pragma unroll
            for (int j = 0; j < 8; ++j) {
                float f = xn[(size_t)(cg * 8 + j) * HW + gc];
                pk[j] = (__bf16)(v ? f : 0.f);
            }
            *(bf16x8*)(dst + cg * 16) = pk;
        }
    }
    __syncthreads();
    const int oc0 = (wv & 3) * 32;
    float* on = out + (size_t)n * 128 * HW;
    if (wv < 4) fb_compute<4>(xs, wf, on, oc0, 0, r0, lane);
    else        fb_compute<3>(xs, wf, on, oc0, 4, r0, lane);
}

extern "C" void kernel_launch(void* const* d_in, const int* in_sizes, int n_in,
                              void* d_out, int out_size, void* d_ws, size_t ws_size,
                              hipStream_t stream) {
    const float* x = (const float*)d_in[0];
    const float* w = (const float*)d_in[1];
    float* out = (float*)d_out;

    if (ws_size >= WB_BYTES) {
        unsigned char* wb = (unsigned char*)d_ws;
        wcvt_kernel<<<(WGRAN + 255) / 256, 256, 0, stream>>>(w, wb);
        conv_kernel<<<CBLK, 512, 0, stream>>>(x, wb, out);
    } else {
        fb_conv_kernel<<<NBLK, 512, 0, stream>>>(x, w, out);
    }
}

// Round 15
// 49.109 us; speedup vs baseline: 1.4364x; 1.0249x over previous
//
#include <hip/hip_runtime.h>
#include <hip/hip_bf16.h>

typedef __bf16 bf16x8 __attribute__((ext_vector_type(8)));
typedef float  f32x4  __attribute__((ext_vector_type(4)));

#define HW       3136
#define IMG_W    56
#define IMG_H    56
#define WGRAN    (9*128*16)                // 16B granules in W (18432)
#define WB_BYTES ((size_t)WGRAN*16)        // 294912
#define CBLK     448                       // conv blocks: 14/img, 4 out-rows each
#define SLOT_B   9216                      // 64 cols * 144 B (64ch bf16 + 16B pad)
#define LDS_B    (6*SLOT_B)                // 55296

#define AS1 __attribute__((address_space(1)))
#define AS3 __attribute__((address_space(3)))

// ---- weight fp32 -> bf16, fragment-major [tap][q32][c][f][lq][l15] 16B granules ----
__global__ __launch_bounds__(256) void wcvt_kernel(const float* __restrict__ w,
                                                   unsigned char* __restrict__ wb) {
    int i = blockIdx.x * 256 + threadIdx.x;          // one 16B granule each
    if (i >= WGRAN) return;
    const int l15 = i & 15, lq = (i >> 4) & 3, f = (i >> 6) & 1;
    const int c   = (i >> 7) & 3, q32 = (i >> 9) & 3, tap = i >> 11;
    const int oc = q32 * 32 + f * 16 + l15;
    const int ch = c * 32 + lq * 8;
    const float* src = w + (size_t)(tap * 128 + oc) * 128 + ch;
    bf16x8 v;
    #pragma unroll
    for (int j = 0; j < 8; ++j) v[j] = (__bf16)src[j];
    *(bf16x8*)(wb + (size_t)i * 16) = v;
}

// ---- stage one (slot, granule) of channel-half H: 8 coalesced 224B fp32 rows ->
//      cvt -> one ds_write_b128 at pitch-144 (bank = 9*col+g : 2-way free). ----
template<int H>
__device__ __forceinline__ void stage_task(unsigned char* xs, const float* __restrict__ xn,
                                           int obase, int s, int g, int lane) {
    const int ar  = obase - 1 + s;                       // absolute image row
    const int arc = min(max(ar, 0), IMG_H - 1);
    const int wcc = min(max(lane - 1, 0), IMG_W - 1);
    const bool v  = (ar >= 0) & (ar < IMG_H) & (lane >= 1) & (lane <= IMG_W);
    const float* bp = xn + (size_t)(H * 64 + g * 8) * HW + arc * IMG_W + wcc;
    bf16x8 pk;
    #pragma unroll
    for (int j = 0; j < 8; ++j) {
        float f = bp[(size_t)j * HW];
        pk[j] = (__bf16)(v ? f : 0.f);
    }
    *(bf16x8*)(xs + s * SLOT_B + lane * 144 + g * 16) = pk;
}

// ---- compute 18 (tap,c) steps of channel-half H, accumulating ----
template<int H>
__device__ __forceinline__ void compute_half(const unsigned char* xs, const unsigned char* wt,
                                             f32x4 acc[2][7], const int vb[7], int lq) {
    bf16x8 aB[2][2];                                     // A ring, 1 step ahead
    #pragma unroll
    for (int f = 0; f < 2; ++f)
        aB[0][f] = *(const bf16x8*)(wt + ((H * 2) * 2 + f) * 1024);

    #pragma unroll
    for (int s = 0; s < 18; ++s) {
        const int tap = s >> 1, cl = s & 1;
        if (s < 17) {                                    // prefetch next step's A
            const int t2 = (s + 1) >> 1, c2 = (s + 1) & 1;
            #pragma unroll
            for (int f = 0; f < 2; ++f)
                aB[(s + 1) & 1][f] = *(const bf16x8*)(wt + t2 * 32768
                                                      + ((H * 2 + c2) * 2 + f) * 1024);
        }
        __builtin_amdgcn_sched_barrier(0);               // pin loads before MFMA cluster

        const int dh = tap / 3 - 1, dw = tap - (tap / 3) * 3 - 1;
        const int offb = dh * SLOT_B + dw * 144 + (cl * 4 + lq) * 16;
        __builtin_amdgcn_s_setprio(1);
        #pragma unroll
        for (int k = 0; k < 7; ++k) {
            bf16x8 b = *(const bf16x8*)(xs + vb[k] + offb);
            acc[0][k] = __builtin_amdgcn_mfma_f32_16x16x32_bf16(aB[s & 1][0], b, acc[0][k], 0, 0, 0);
            acc[1][k] = __builtin_amdgcn_mfma_f32_16x16x32_bf16(aB[s & 1][1], b, acc[1][k], 0, 0, 0);
        }
        __builtin_amdgcn_s_setprio(0);
        __builtin_amdgcn_sched_barrier(0);
    }
}

// ---- conv: 448 blocks x one 4-row tile (224 pos); 8 waves = 4 oc-groups x 2 pos-halves
//      (K=7); channel-split LDS (2 halves x 64ch, 55KB) -> 2 blocks/CU, 16 waves/CU ----
__global__ __launch_bounds__(512, 4) void conv_kernel(const float* __restrict__ x,
                                                      const unsigned char* __restrict__ wb,
                                                      float* __restrict__ out) {
    __shared__ __align__(16) unsigned char xs[LDS_B];    // 6 slots x 64 cols x 144B
    const int t = threadIdx.x, lane = t & 63, wv = t >> 6;  // 8 waves
    const int l15 = lane & 15, lq = lane >> 4;
    const int b = blockIdx.x;
    const int swz = (b & 7) * 56 + (b >> 3);             // XCD-contiguous: 4 img/XCD
    const int img = swz / 14, loc = swz - img * 14;
    const int obase = loc * 4;                           // out rows obase..obase+3

    const float* xn = x + (size_t)img * 128 * HW;
    const int q32 = wv & 3;                              // 32-oc group
    const int g7  = wv >> 2;                             // pos-half (7 frags)
    const unsigned char* wt = wb + (size_t)q32 * 8192 + lane * 16;

    int vb[7];
    #pragma unroll
    for (int k = 0; k < 7; ++k) {
        int p = (g7 * 7 + k) * 16 + l15;                 // 0..223 tile-local pos
        int pr = p / 56, pc = p - pr * 56;
        vb[k] = (pr + 1) * SLOT_B + (pc + 1) * 144;
    }

    f32x4 acc[2][7];
    #pragma unroll
    for (int f = 0; f < 2; ++f)
        #pragma unroll
        for (int k = 0; k < 7; ++k) acc[f][k] = (f32x4){0.f, 0.f, 0.f, 0.f};

    // ---- half 0: stage (48 tasks, 6/wave), compute ----
    #pragma unroll
    for (int i = 0; i < 6; ++i) {
        int task = wv + 8 * i;                           // 0..47
        stage_task<0>(xs, xn, obase, task >> 3, task & 7, lane);
    }
    __syncthreads();
    compute_half<0>(xs, wt, acc, vb, lq);
    __syncthreads();                                     // all waves done reading h0

    // ---- half 1 ----
    #pragma unroll
    for (int i = 0; i < 6; ++i) {
        int task = wv + 8 * i;
        stage_task<1>(xs, xn, obase, task >> 3, task & 7, lane);
    }
    __syncthreads();
    compute_half<1>(xs, wt, acc, vb, lq);

    // ---- store ----
    float* on = out + (size_t)img * 128 * HW;
    #pragma unroll
    for (int f = 0; f < 2; ++f)
        #pragma unroll
        for (int k = 0; k < 7; ++k) {
            int p = (g7 * 7 + k) * 16 + l15;
            int pr = p / 56, pc = p - pr * 56;
            int pos = (obase + pr) * 56 + pc;
            int oc  = q32 * 32 + f * 16 + lq * 4;
            #pragma unroll
            for (int rr = 0; rr < 4; ++rr)
                on[(size_t)(oc + rr) * HW + pos] = acc[f][k][rr];
        }
}

// ================= fallback (ws too small): self-contained, fp32 weights =================
#define PITCH  272
#define LDSB   (4*64*PITCH)
#define NBLK   896

template<int NPF>
__device__ __forceinline__ void fb_compute(const unsigned char* xs, const float* wf,
                                           float* on, int oc0, int pf0, int r0, int lane) {
    const int l15 = lane & 15, lq = lane >> 4;
    int spb[NPF];
    #pragma unroll
    for (int k = 0; k < NPF; ++k) {
        int p = (pf0 + k) * 16 + l15;
        int r = p / 56, w = p - r * 56;
        spb[k] = ((r + 1) * 64 + (w + 1)) * PITCH + lq * 16;
    }
    f32x4 acc[2][NPF];
    #pragma unroll
    for (int f = 0; f < 2; ++f)
        #pragma unroll
        for (int k = 0; k < NPF; ++k) acc[f][k] = (f32x4){0.f, 0.f, 0.f, 0.f};
    #pragma unroll 3
    for (int tap = 0; tap < 9; ++tap) {
        const int offb  = ((tap / 3) * 64 + (tap % 3) - 65) * PITCH;
        const int wbase = tap * 16384 + oc0 * 128 + l15 * 128 + lq * 8;
        #pragma unroll
        for (int c = 0; c < 4; ++c) {
            bf16x8 a[2];
            #pragma unroll
            for (int f = 0; f < 2; ++f) {
                const float* p = wf + wbase + f * 2048 + c * 32;
                #pragma unroll
                for (int j = 0; j < 8; ++j) a[f][j] = (__bf16)p[j];
            }
            #pragma unroll
            for (int k = 0; k < NPF; ++k) {
                bf16x8 b = *(const bf16x8*)(xs + spb[k] + offb + c * 64);
                #pragma unroll
                for (int f = 0; f < 2; ++f)
                    acc[f][k] = __builtin_amdgcn_mfma_f32_16x16x32_bf16(a[f], b, acc[f][k], 0, 0, 0);
            }
        }
    }
    #pragma unroll
    for (int f = 0; f < 2; ++f)
        #pragma unroll
        for (int k = 0; k < NPF; ++k) {
            int pos = r0 * 56 + (pf0 + k) * 16 + l15;
            int oc  = oc0 + f * 16 + lq * 4;
            #pragma unroll
            for (int rr = 0; rr < 4; ++rr)
                on[(size_t)(oc + rr) * HW + pos] = acc[f][k][rr];
        }
}

__global__ __launch_bounds__(512, 4) void fb_conv_kernel(const float* __restrict__ x,
                                                         const float* __restrict__ wf,
                                                         float* __restrict__ out) {
    __shared__ __align__(16) unsigned char xs[LDSB];
    const int tid = threadIdx.x, lane = tid & 63, wv = tid >> 6;
    const int bid = blockIdx.x;
    const int swz = (bid & 7) * (NBLK / 8) + (bid >> 3);
    const int n = swz / 28, rp = swz - n * 28, r0 = rp * 2;
    if (wv < 4) {
        const float* xn = x + (size_t)n * 128 * HW;
        const int ar = r0 - 1 + wv, wi = lane - 1;
        const bool v = (ar >= 0) & (ar < IMG_H) & (wi >= 0) & (wi < IMG_W);
        const int gc = min(max(ar, 0), IMG_H - 1) * IMG_W + min(max(wi, 0), IMG_W - 1);
        unsigned char* dst = xs + (wv * 64 + lane) * PITCH;
        #pragma unroll
        for (int cg = 0; cg < 16; ++cg) {
            bf16x8 pk;
            #pragma unroll
            for (int j = 0; j < 8; ++j) {
                float f = xn[(size_t)(cg * 8 + j) * HW + gc];
                pk[j] = (__bf16)(v ? f : 0.f);
            }
            *(bf16x8*)(dst + cg * 16) = pk;
        }
    }
    __syncthreads();
    const int oc0 = (wv & 3) * 32;
    float* on = out + (size_t)n * 128 * HW;
    if (wv < 4) fb_compute<4>(xs, wf, on, oc0, 0, r0, lane);
    else        fb_compute<3>(xs, wf, on, oc0, 4, r0, lane);
}

extern "C" void kernel_launch(void* const* d_in, const int* in_sizes, int n_in,
                              void* d_out, int out_size, void* d_ws, size_t ws_size,
                              hipStream_t stream) {
    const float* x = (const float*)d_in[0];
    const float* w = (const float*)d_in[1];
    float* out = (float*)d_out;

    if (ws_size >= WB_BYTES) {
        unsigned char* wb = (unsigned char*)d_ws;
        wcvt_kernel<<<(WGRAN + 255) / 256, 256, 0, stream>>>(w, wb);
        conv_kernel<<<CBLK, 512, 0, stream>>>(x, wb, out);
    } else {
        fb_conv_kernel<<<NBLK, 512, 0, stream>>>(x, w, out);
    }
}